// Round 5
// baseline (170.443 us; speedup 1.0000x reference)
//
#include <hip/hip_runtime.h>

// PSAMask collect: out[n, i*65+j, h, w] = x[n, (i-h+64)*129 + (j-w+64), h, w]
// Pure gather (mask window fully covers offsets). R5: block = (n, i, h-PAIR).
// Two async-staged trapezoids (68KB LDS, 1024 thr, 2 blocks/CU = same 32
// waves/CU as R2); stores fuse rows h0,h0+1 into 520B contiguous segments
// per j -> interior lines full, half the partial-line ends. Probes whether
// cross-block write-merge was the missing ~15% of traffic.

constexpr int H = 65, W = 65, MH = 129, MW = 129, HALF = 64;
constexpr int HW = H * W;            // 4225
constexpr int PITCH = 66;            // skew-read lane delta -65: conflict-free
constexpr int TILE_F = MH * PITCH;   // 8514 floats = 34,056 B per trapezoid
constexpr int NPAIR = 33;            // 32 h-pairs + 1 single (h = 64)
constexpr int NWG = 4 * H * NPAIR;   // 8580

__device__ __forceinline__ void ldsld(const float* g, float* l) {
    __builtin_amdgcn_global_load_lds(
        (const __attribute__((address_space(1))) unsigned int*)g,
        (__attribute__((address_space(3))) unsigned int*)l, 4, 0, 0);
}

__global__ __launch_bounds__(1024, 2)
void psamask_collect(const float* __restrict__ x, float* __restrict__ out) {
    extern __shared__ float lds[];   // 2 * 8514 * 4 = 68,112 B

    // Bijective XCD-aware swizzle (8580 % 8 == 4 -> m204 formula)
    constexpr int NX = 8, q = NWG / NX, r = NWG % NX;   // 1072, 4
    int b = blockIdx.x;
    int xcd = b % NX, idx = b / NX;
    int logical = (xcd < r ? xcd * (q + 1) : r * (q + 1) + (xcd - r) * q) + idx;

    int n   = logical / (H * NPAIR);
    int rem = logical - n * (H * NPAIR);
    int i   = rem / NPAIR;
    int hp  = rem - i * NPAIR;
    int h0  = 2 * hp;
    int nh  = (hp == NPAIR - 1) ? 1 : 2;   // last block: single h = 64

    int half = threadIdx.x >> 9;           // which h this thread stages
    int w8   = (threadIdx.x >> 6) & 7;
    int lane = threadIdx.x & 63;

    if (half < nh) {
        int h  = h0 + half;
        int Mh = i - h + HALF;             // in [0,128]
        const float* src = x + (size_t)(n * (MH * MW) + Mh * MW) * HW + h * W;
        float* buf = lds + half * TILE_F;
        // Trapezoid: row u used for w in [max(0,64-u), min(65,129-u))
        for (int u = w8; u < MH; u += 8) {
            int lo = HALF - u; if (lo < 0) lo = 0;
            int hi = MH - u;   if (hi > W) hi = W;
            const float* rowp = src + (size_t)u * HW;
            for (int w0 = lo; w0 < hi; w0 += 64) {
                int w = w0 + lane;
                if (w < hi) ldsld(rowp + w, &buf[u * PITCH + w0]);
            }
        }
    }
    __syncthreads();   // drains vmcnt(0): both trapezoids resident

    float* dstb = out + (size_t)n * HW * HW + (size_t)(i * W) * HW + h0 * W;
    if (nh == 2) {
        // Fused store: 130 contiguous floats per j (rows h0, h0+1)
        for (int f = (int)threadIdx.x; f < W * 130; f += 1024) {
            int j = f / 130;
            int t = f - j * 130;           // 0..129 within the fused row
            int e = t >= W;                // which h
            int w = t - e * W;
            int u = j - w + HALF;
            dstb[(size_t)j * HW + t] = lds[e * TILE_F + u * PITCH + w];
        }
    } else {
        for (int f = (int)threadIdx.x; f < W * W; f += 1024) {
            int j = f / W;
            int w = f - j * W;
            int u = j - w + HALF;
            dstb[(size_t)j * HW + w] = lds[u * PITCH + w];
        }
    }
}

extern "C" void kernel_launch(void* const* d_in, const int* in_sizes, int n_in,
                              void* d_out, int out_size, void* d_ws, size_t ws_size,
                              hipStream_t stream) {
    const float* x = (const float*)d_in[0];
    float* out = (float*)d_out;
    (void)in_sizes; (void)n_in; (void)out_size; (void)d_ws; (void)ws_size;
    psamask_collect<<<dim3(NWG), dim3(1024), 2 * TILE_F * sizeof(float), stream>>>(x, out);
}

// Round 6
// 168.744 us; speedup vs baseline: 1.0101x; 1.0101x over previous
//
#include <hip/hip_runtime.h>

// PSAMask collect: out[n, i*65+j, h, w] = x[n, (i-h+64)*129 + (j-w+64), h, w]
// R6: break the scalar per-element store path (theory: 1 ds_read_b32 +
// 1 store_dword per element saturates CU issue at ~1/cy). Output-order LDS
// layout (skew at write): elem (u,w) -> lds[(u+w-64)*P2 + w + s_j]; store as
// 15 aligned dwordx4 + 5 edge dwords per row. Reg-staged loads (batched,
// coalesced) since global_load_lds can't scatter.

constexpr int H = 65, W = 65, MH = 129, MW = 129, HALF = 64;
constexpr int HW = H * W;          // 4225
constexpr int P2 = 68;             // LDS pitch (floats), %4==0; row use <= 67
constexpr int NWG = 4 * H * H;     // 16900

__global__ __launch_bounds__(512, 8)
void psamask_collect(const float* __restrict__ x, float* __restrict__ out) {
    __shared__ float lds[H * P2];  // 65*68*4 = 17,680 B

    // Bijective XCD-aware swizzle (16900 % 8 == 4 -> m204 formula)
    constexpr int NX = 8, q = NWG / NX, r = NWG % NX;
    int b = blockIdx.x;
    int xcd = b % NX, idx = b / NX;
    int logical = (xcd < r ? xcd * (q + 1) : r * (q + 1) + (xcd - r) * q) + idx;

    int n   = logical / (H * H);
    int rem = logical - n * (H * H);
    int i   = rem / H;
    int h   = rem - i * H;
    int Mh  = i - h + HALF;            // in [0,128]

    const float* src = x + (size_t)(n * (MH * MW) + Mh * MW) * HW + h * W;
    float* dst = out + (size_t)n * HW * HW + (size_t)(i * W) * HW + (size_t)h * W;
    int base0 = (n + i + h) & 3;       // out row j starts at element = base0+j (mod 4)

    int wv   = threadIdx.x >> 6;
    int lane = threadIdx.x & 63;

    // ---- Load: 17 batched coalesced dword loads per wave (rows u = wv+8*r2),
    // then scattered ds_write_b32 (stride 69 -> 2 lanes/bank, free).
    float v[17];
    #pragma unroll
    for (int r2 = 0; r2 < 17; ++r2) {
        int u = wv + 8 * r2;
        if (u < MH) {
            int lo = HALF - u; if (lo < 0) lo = 0;
            int hi = MH - u;   if (hi > W) hi = W;
            int w = lo + lane;
            if (w < hi) v[r2] = src[(size_t)u * HW + w];
        }
    }
    float vx;                           // row u=64 has 65 elems; lane coverage is 64
    bool actx = (wv == 0 && lane == 0);
    if (actx) vx = src[(size_t)64 * HW + 64];

    #pragma unroll
    for (int r2 = 0; r2 < 17; ++r2) {
        int u = wv + 8 * r2;
        if (u < MH) {
            int lo = HALF - u; if (lo < 0) lo = 0;
            int hi = MH - u;   if (hi > W) hi = W;
            int w = lo + lane;
            if (w < hi) {
                int j = u + w - HALF;          // in [0,65)
                int s = (base0 + j) & 3;       // keeps x4 reads 16B-aligned
                lds[j * P2 + w + s] = v[r2];
            }
        }
    }
    if (actx) {
        int s = (base0 + 64) & 3;
        lds[64 * P2 + 64 + s] = vx;
    }
    __syncthreads();

    // ---- Store: per row j, 15 aligned dwordx4 (w in [a_j, a_j+60)) + 5 edges.
    constexpr int MAIN = H * 15;       // 975
    for (int g = (int)threadIdx.x; g < MAIN; g += 512) {
        int j = (g * 17477) >> 18;     // g/15, exact for g<975
        int k = g - 15 * j;
        int m = (base0 + j) & 3;
        int a = (4 - m) & 3;
        int w = a + 4 * k;             // (dst elem index) % 4 == 0
        // lds idx = j*68 + (m?4:0) + 4k -> 16B aligned
        float4 val = *reinterpret_cast<const float4*>(&lds[j * P2 + w + m]);
        *reinterpret_cast<float4*>(&dst[(size_t)j * HW + w]) = val;
    }
    constexpr int EDGE = H * 5;        // 325
    for (int e = (int)threadIdx.x; e < EDGE; e += 512) {
        int j = (e * 52429) >> 18;     // e/5, exact for e<325
        int d = e - 5 * j;
        int m = (base0 + j) & 3;
        int a = (4 - m) & 3;
        int w = d + (d >= a ? 60 : 0); // [0,a) lead + [a+60,65) tail
        dst[(size_t)j * HW + w] = lds[j * P2 + w + m];
    }
}

extern "C" void kernel_launch(void* const* d_in, const int* in_sizes, int n_in,
                              void* d_out, int out_size, void* d_ws, size_t ws_size,
                              hipStream_t stream) {
    const float* x = (const float*)d_in[0];
    float* out = (float*)d_out;
    (void)in_sizes; (void)n_in; (void)out_size; (void)d_ws; (void)ws_size;
    psamask_collect<<<dim3(NWG), dim3(512), 0, stream>>>(x, out);
}